// Round 8
// baseline (370.269 us; speedup 1.0000x reference)
//
#include <hip/hip_runtime.h>

typedef _Float16 h8v __attribute__((ext_vector_type(8)));
typedef _Float16 h4v __attribute__((ext_vector_type(4)));
typedef float    f4v __attribute__((ext_vector_type(4)));

#define MFMA16(a,b,c) __builtin_amdgcn_mfma_f32_16x16x32_f16((a),(b),(c),0,0,0)
#define NEGF (-1e30f)

#define MEM 1000
#define KEY 64
#define VAL 128
#define DIN 512
#define BS  512
#define BQ  65536

// Fragment-major B layouts: element (F,KS,lane,j) at ((F*nKS+KS)*64+lane)*8+j
// holds B[n = F*16 + (lane&15)][k = KS*32 + (lane>>4)*8 + j]  -> every MFMA
// B-fragment load is lane-contiguous (16 B/lane, 1 KB/wave), and LINEAR for
// global_load_lds.
//
// SWAPPED-QK (verified R5, absmax unchanged): MFMA16(Kfrag, Qfrag) computes
// P^T with P[query=lane&15][slot = f*16 + quad*4 + r] lane-local. valF's
// k-dim is permuted in prep3 so PV's A-frag is the lane's OWN S values.
//
// R8: R7 ran at 1 block/CU (148 KB LDS) -> 2 waves/SIMD, ~85 us of SIMD
// idle at block-wide barriers/chains (Mfma 12%, VALU 21%, occ 19%).
// This version shrinks the block to 64 KB LDS -> 2 blocks/CU, 4 waves/SIMD,
// ONE block-round: feature phase uses 2x32KB double-buffered WTf quarters;
// attention uses 16 chunks of 64 slots (K/V dbuf 48 KB); epilogue reads c1F
// straight from L2 and overlays scratch on the dead K/V area.

typedef __attribute__((address_space(1))) const unsigned int guint;
typedef __attribute__((address_space(3))) unsigned int luint;

// async global->LDS, 16 B/lane: LDS gets [uniform l + lane*16B] = g[lane*16B]
__device__ __forceinline__ void gld16(const _Float16* g, _Float16* l)
{
  __builtin_amdgcn_global_load_lds((guint*)g, (luint*)l, 16, 0, 0);
}

__device__ __forceinline__ h8v cvt8(const float* p)
{
  f4v u = *(const f4v*)p;
  f4v v = *(const f4v*)(p + 4);
  h8v a;
  a[0] = (_Float16)u.x; a[1] = (_Float16)u.y; a[2] = (_Float16)u.z; a[3] = (_Float16)u.w;
  a[4] = (_Float16)v.x; a[5] = (_Float16)v.y; a[6] = (_Float16)v.z; a[7] = (_Float16)v.w;
  return a;
}

__device__ __forceinline__ h8v cvt8nt(const float* p)
{
  f4v u = __builtin_nontemporal_load((const f4v*)p);
  f4v v = __builtin_nontemporal_load((const f4v*)(p + 4));
  h8v a;
  a[0] = (_Float16)u.x; a[1] = (_Float16)u.y; a[2] = (_Float16)u.z; a[3] = (_Float16)u.w;
  a[4] = (_Float16)v.x; a[5] = (_Float16)v.y; a[6] = (_Float16)v.z; a[7] = (_Float16)v.w;
  return a;
}

// ---------------------------------------------------------------------------
// prep1: fragment-major weights, Wck = baseW@kpW fused, bcomb, ranks, zero
// ---------------------------------------------------------------------------
__global__ void k_prep1(const float* __restrict__ baseW, const float* __restrict__ base_b,
                        const float* __restrict__ kpW, const float* __restrict__ kp_b,
                        const float* __restrict__ vpW, const float* __restrict__ c1W,
                        const float* __restrict__ c2W, const float* __restrict__ age,
                        _Float16* __restrict__ WTf, float* __restrict__ bcomb,
                        _Float16* __restrict__ vpWt, _Float16* __restrict__ c1F,
                        _Float16* __restrict__ c2F, int* __restrict__ ranks,
                        float* __restrict__ out0)
{
  long id = (long)blockIdx.x * 256 + threadIdx.x;
  if (id < 65536) {                        // WTf: [baseW^T | Wck^T], n=128, k=512 (KS=16)
    int h = (int)id;
    int j = h & 7, lane = (h >> 3) & 63, KS = (h >> 9) & 15, F = h >> 13;
    int n = F * 16 + (lane & 15);
    int k = KS * 32 + ((lane >> 4) << 3) + j;
    float v;
    if (n < 64) v = baseW[(size_t)k * 64 + n];
    else {
      int nn = n - 64;
      const float* br = baseW + (size_t)k * 64;
      float s = 0.f;
      for (int t = 0; t < 64; ++t) s += br[t] * kpW[t * 64 + nn];
      v = s;
    }
    WTf[h] = (_Float16)v;
  } else if (id < 65664) {                 // bcomb
    int i = (int)(id - 65536);
    if (i < 64) bcomb[i] = base_b[i];
    else {
      int n = i - 64;
      float s = kp_b[n];
      for (int t = 0; t < 64; ++t) s += base_b[t] * kpW[t * 64 + n];
      bcomb[i] = s;
    }
  } else if (id < 90240) {                 // c1F: n=128 (F=8), k=192 (KS=6)
    int h = (int)(id - 65664);
    int j = h & 7, lane = (h >> 3) & 63, KS = (h >> 9) % 6, F = (h >> 9) / 6;
    int n = F * 16 + (lane & 15);
    int k = KS * 32 + ((lane >> 4) << 3) + j;
    c1F[h] = (_Float16)c1W[(size_t)k * 128 + n];
  } else if (id < 98432) {                 // c2F: n=64 (F=4), k=128 (KS=4)
    int h = (int)(id - 90240);
    int j = h & 7, lane = (h >> 3) & 63, KS = (h >> 9) & 3, F = h >> 11;
    int n = F * 16 + (lane & 15);
    int k = KS * 32 + ((lane >> 4) << 3) + j;
    c2F[h] = (_Float16)c2W[(size_t)k * 64 + n];
  } else if (id < 114816) {                // vpWt[n][k] (row-major transposed, prep2 only)
    long i = id - 98432;
    int n = (int)(i >> 7), k = (int)(i & 127);
    vpWt[i] = (_Float16)vpW[(size_t)k * 128 + n];
  } else if (id < 115816) {                // stable ranks (lax.top_k order)
    int jx = (int)(id - 114816);
    float aj = age[jx];
    int r = 0;
    for (int i2 = 0; i2 < MEM; ++i2) {
      float ai = age[i2];
      r += (ai > aj) || (ai == aj && i2 < jx);
    }
    ranks[jx] = r;
  } else if (id == 115816) {
    *out0 = 0.f;
  }
}

// ---------------------------------------------------------------------------
// prep2: pkeys = sx@Wck + bck ; pvals = sy@vpW + vp_b
// ---------------------------------------------------------------------------
__global__ __launch_bounds__(64) void k_prep2(
    const float* __restrict__ sx, const float* __restrict__ sy,
    const _Float16* __restrict__ WTf, const float* __restrict__ bcomb,
    const _Float16* __restrict__ vpWt, const float* __restrict__ vp_b,
    float* __restrict__ pkeys, float* __restrict__ pvals)
{
  const int lane = threadIdx.x, quad = lane >> 4, l15 = lane & 15;
  const f4v fz = {0.f, 0.f, 0.f, 0.f};
  if (blockIdx.x < 32) {
    const int m0 = blockIdx.x * 16;
    f4v acc[4];
    #pragma unroll
    for (int f = 0; f < 4; ++f) acc[f] = fz;
    const float* xr = sx + (size_t)(m0 + l15) * DIN;
    #pragma unroll 4
    for (int ks = 0; ks < 16; ++ks) {
      int k0 = ks * 32 + quad * 8;
      h8v a = cvt8(xr + k0);
      #pragma unroll
      for (int f = 0; f < 4; ++f) {
        h8v b = *(const h8v*)(WTf + (size_t)((((4 + f) * 16) + ks) * 64 + lane) * 8);
        acc[f] = MFMA16(a, b, acc[f]);
      }
    }
    #pragma unroll
    for (int f = 0; f < 4; ++f) {
      int col = f * 16 + l15;
      float bb = bcomb[64 + col];
      #pragma unroll
      for (int r = 0; r < 4; ++r)
        pkeys[(size_t)(m0 + quad * 4 + r) * KEY + col] = acc[f][r] + bb;
    }
  } else {
    const int m0 = (blockIdx.x - 32) * 16;
    f4v acc[8];
    #pragma unroll
    for (int f = 0; f < 8; ++f) acc[f] = fz;
    const float* yr = sy + (size_t)(m0 + l15) * VAL;
    #pragma unroll
    for (int ks = 0; ks < 4; ++ks) {
      int k0 = ks * 32 + quad * 8;
      h8v a = cvt8(yr + k0);
      #pragma unroll
      for (int f = 0; f < 8; ++f) {
        h8v b = *(const h8v*)(vpWt + (size_t)(f * 16 + l15) * 128 + k0);
        acc[f] = MFMA16(a, b, acc[f]);
      }
    }
    #pragma unroll
    for (int f = 0; f < 8; ++f) {
      int col = f * 16 + l15;
      float bb = vp_b[col];
      #pragma unroll
      for (int r = 0; r < 4; ++r)
        pvals[(size_t)(m0 + quad * 4 + r) * VAL + col] = acc[f][r] + bb;
    }
  }
}

// ---------------------------------------------------------------------------
// prep3: scatter memory into fragment-major keysF / valF (zero-padded)
// keysF: n=1024 slots (F=64), k=KEY 64 (KS=2)  -- tile idx = F*2+KS
// valF : n=VAL 128 (F=8),     k=1024 slots (KS=32), k-dim PERMUTED per
//        32-slot step so PV A-frags are lane-local under swapped QK:
//        frag pos (quad,j) holds slot KS*32 + (j>>2)*16 + quad*4 + (j&3).
//        tile idx = F*32+KS.
// ---------------------------------------------------------------------------
__global__ void k_prep3(const int* __restrict__ ranks, const float* __restrict__ pk,
                        const float* __restrict__ pv, const float* __restrict__ memK,
                        const float* __restrict__ memV,
                        _Float16* __restrict__ keysF, _Float16* __restrict__ valF)
{
  int id = blockIdx.x * 256 + threadIdx.x;
  if (id < 65536) {
    int j = id & 7, lane = (id >> 3) & 63, KS = (id >> 9) & 1, F = id >> 10;
    int n = F * 16 + (lane & 15);                  // mem slot
    int k = KS * 32 + ((lane >> 4) << 3) + j;      // key col
    float v = 0.f;
    if (n < MEM) {
      int rk = ranks[n];
      v = (rk < BS) ? pk[(size_t)rk * KEY + k] : memK[(size_t)n * KEY + k];
    }
    keysF[id] = (_Float16)v;
  } else {
    int h = id - 65536;
    int j = h & 7, lane = (h >> 3) & 63, KS = (h >> 9) & 31, F = h >> 14;
    int nv = F * 16 + (lane & 15);                 // val col
    // permuted slot within the 32-slot k-step (see header comment)
    int jm = KS * 32 + ((j >> 2) << 4) + (((lane >> 4)) << 2) + (j & 3);
    float v = 0.f;
    if (jm < MEM) {
      int rk = ranks[jm];
      v = (rk < BS) ? pv[(size_t)rk * VAL + nv] : memV[(size_t)jm * VAL + nv];
    }
    valF[h] = (_Float16)v;
  }
}

// ---------------------------------------------------------------------------
// fused: features + attention + controller, 16 q/wave, 8 waves/block,
// grid 512, LDS 64 KB -> 2 blocks/CU (4 waves/SIMD), ONE round.
//  phase 1: WTf staged as 4 double-buffered 32 KB quarters (ks-groups of 4)
//  phase 2: 16 chunks of 64 slots, K/V dbuf 48 KB, qf stash at [48K,64K)
//  phase 3: c1F from L2 directly; per-wave scratch overlays dead K/V area
// ---------------------------------------------------------------------------
__global__ __launch_bounds__(512, 4) void k_fused(
    const float* __restrict__ qx, const float* __restrict__ qy,
    const _Float16* __restrict__ WTf, const float* __restrict__ bcomb,
    const float* __restrict__ c1_b, const float* __restrict__ c2_b,
    const float* __restrict__ c3W, const float* __restrict__ c3b,
    const _Float16* __restrict__ c1F, const _Float16* __restrict__ c2F,
    const _Float16* __restrict__ keysF, const _Float16* __restrict__ valF,
    float* __restrict__ dout)
{
  __shared__ __align__(16) char smem[65536];
  // phase 1: Wq[0]=[0,32K), Wq[1]=[32K,64K)
  _Float16* const Wq0 = (_Float16*)smem;
  _Float16* const Wq1 = (_Float16*)(smem + 32768);
  // phase 2: K dbuf 2x8K at 0, V dbuf 2x16K at 16K, qf stash 16K at 48K
  _Float16* const K0 = (_Float16*)smem;                  // 4096 halves
  _Float16* const K1 = (_Float16*)(smem + 8192);
  _Float16* const V0 = (_Float16*)(smem + 16384);        // 8192 halves
  _Float16* const V1 = (_Float16*)(smem + 32768);

  const int tid  = threadIdx.x;
  const int wid  = tid >> 6;
  const int lane = tid & 63;
  const int quad = lane >> 4;
  const int l15  = lane & 15;

  _Float16* const qstash = (_Float16*)(smem + 49152 + wid * 2048);  // 2x512 h
  // phase 3 per-wave scratch (dead K/V area): 2176 + 1152 halves
  _Float16* const P_s  = (_Float16*)(smem + wid * 6656);
  _Float16* const h2_s = P_s + 2176;

  const int tile = blockIdx.x * 8 + wid;       // one 16-query tile per wave
  const int q0   = tile * 16;

  float* out_pred = dout + 1;
  float* out_ret  = dout + 1 + BQ;
  const f4v fz = {0.f, 0.f, 0.f, 0.f};

  // ================= phase 1: features (dbuf 32 KB quarters) =============
  // quarter q covers ks in [q*4, q*4+4); tile (f,ksq) at LDS (f*4+ksq)*512
  #pragma unroll
  for (int i = 0; i < 4; ++i) {                // stage Q0 -> Wq0
    const int t = wid * 4 + i;
    const int f = t >> 2, ksq = t & 3;
    gld16(WTf + (size_t)(f * 16 + ksq) * 512 + lane * 8, Wq0 + t * 512);
  }
  asm volatile("s_waitcnt vmcnt(0)" ::: "memory");
  __syncthreads();

  f4v acc[8];
  #pragma unroll
  for (int f = 0; f < 8; ++f) acc[f] = fz;
  const float* xr = qx + (size_t)(q0 + l15) * DIN;

  #pragma unroll
  for (int q = 0; q < 4; ++q) {
    _Float16* const Wb = (q & 1) ? Wq1 : Wq0;
    _Float16* const Wn = (q & 1) ? Wq0 : Wq1;
    if (q < 3) {                               // stage next quarter
      #pragma unroll
      for (int i = 0; i < 4; ++i) {
        const int t = wid * 4 + i;
        const int f = t >> 2, ksq = t & 3;
        gld16(WTf + (size_t)(f * 16 + (q + 1) * 4 + ksq) * 512 + lane * 8,
              Wn + t * 512);
      }
    }
    #pragma unroll
    for (int ksq = 0; ksq < 4; ++ksq) {
      const int ks = q * 4 + ksq;
      h8v a = cvt8nt(xr + ks * 32 + quad * 8);
      #pragma unroll
      for (int f = 0; f < 8; ++f) {
        h8v b = *(const h8v*)(Wb + (size_t)((f * 4 + ksq) * 64 + lane) * 8);
        acc[f] = MFMA16(a, b, acc[f]);
      }
    }
    asm volatile("s_waitcnt vmcnt(0)" ::: "memory");
    __syncthreads();
  }

  // C-layout -> A-frag registers via per-wave LDS transpose (Wq area dead).
  // qf frags go to the qstash (live through phase 2), pq stay in registers.
  _Float16* tbuf = (_Float16*)(smem + wid * 4352);  // 2176 halves
  h8v pq0, pq1;
  {
    #pragma unroll
    for (int f = 0; f < 8; ++f) {
      float bb = bcomb[f * 16 + l15];
      #pragma unroll
      for (int r = 0; r < 4; ++r)
        tbuf[(quad * 4 + r) * 136 + f * 16 + l15] = (_Float16)(acc[f][r] + bb);
    }
    h8v qf0 = *(const h8v*)&tbuf[l15 * 136 +  0 + quad * 8];
    h8v qf1 = *(const h8v*)&tbuf[l15 * 136 + 32 + quad * 8];
    pq0 = *(const h8v*)&tbuf[l15 * 136 + 64 + quad * 8];
    pq1 = *(const h8v*)&tbuf[l15 * 136 + 96 + quad * 8];
    *(h8v*)&qstash[0 * 512 + lane * 8] = qf0;
    *(h8v*)&qstash[1 * 512 + lane * 8] = qf1;
  }
  __syncthreads();   // tbuf reads done -> K/V staging may overwrite [0,48K)

  // ================= phase 2: attention (16 chunks of 64 slots) ==========
  // chunk c: K tiles keysF[(c*8+i)*512], i 0..7 -> Kbuf + i*512
  //          V tiles valF[(v*32 + c*2 + ks2)*512] -> Vbuf + (v*2+ks2)*512
  // staging: 24 tiles / 8 waves = 3 per wave
  #pragma unroll
  for (int i = 0; i < 3; ++i) {                // stage chunk 0
    const int t = wid * 3 + i;
    if (t < 8) gld16(keysF + (size_t)t * 512 + lane * 8, K0 + t * 512);
    else {
      const int tv = t - 8;
      gld16(valF + (size_t)((tv >> 1) * 32 + (tv & 1)) * 512 + lane * 8,
            V0 + tv * 512);
    }
  }
  asm volatile("s_waitcnt vmcnt(0)" ::: "memory");
  __syncthreads();

  float rm = NEGF, rl = 0.f;                   // scalars (query = l15)
  f4v O[8];
  #pragma unroll
  for (int v = 0; v < 8; ++v) O[v] = fz;

  #pragma unroll 1
  for (int c = 0; c < 16; ++c) {
    const int cur = c & 1;
    _Float16* const Kc = cur ? K1 : K0;
    _Float16* const Vc = cur ? V1 : V0;
    _Float16* const Kn = cur ? K0 : K1;
    _Float16* const Vn = cur ? V0 : V1;

    if (c < 15) {                              // prefetch next chunk
      const int nc = c + 1;
      #pragma unroll
      for (int i = 0; i < 3; ++i) {
        const int t = wid * 3 + i;
        if (t < 8)
          gld16(keysF + (size_t)(nc * 8 + t) * 512 + lane * 8, Kn + t * 512);
        else {
          const int tv = t - 8;
          gld16(valF + (size_t)((tv >> 1) * 32 + nc * 2 + (tv & 1)) * 512 + lane * 8,
                Vn + tv * 512);
        }
      }
    }

    // ---- QK^T (swapped): 8 MFMA, S lane-local ----
    f4v S[4];
    #pragma unroll
    for (int f = 0; f < 4; ++f) S[f] = fz;
    #pragma unroll
    for (int f = 0; f < 4; ++f) {
      h8v b0 = *(const h8v*)(Kc + (size_t)(f * 2 + 0) * 512 + lane * 8);
      h8v b1 = *(const h8v*)(Kc + (size_t)(f * 2 + 1) * 512 + lane * 8);
      S[f] = MFMA16(b0, pq0, S[f]);
      S[f] = MFMA16(b1, pq1, S[f]);
    }

    // ---- register softmax (16 vals/lane) ----
    float cm = NEGF;
    #pragma unroll
    for (int f = 0; f < 4; ++f) {
      const int sb = c * 64 + f * 16 + quad * 4;
      #pragma unroll
      for (int r = 0; r < 4; ++r) {
        float s = (sb + r < MEM) ? S[f][r] : NEGF;
        S[f][r] = s;
        cm = fmaxf(cm, s);
      }
    }
    cm = fmaxf(cm, __shfl_xor(cm, 16));
    cm = fmaxf(cm, __shfl_xor(cm, 32));
    float mn = fmaxf(rm, cm);
    float al = __expf(rm - mn);
    rm = mn;
    float psl = 0.f;
    #pragma unroll
    for (int f = 0; f < 4; ++f)
      #pragma unroll
      for (int r = 0; r < 4; ++r) {
        float p = __expf(S[f][r] - mn);
        S[f][r] = p;
        psl += p;
      }
    rl = rl * al + psl;
    float alO[4];
    #pragma unroll
    for (int r = 0; r < 4; ++r) alO[r] = __shfl(al, quad * 4 + r);
    #pragma unroll
    for (int v = 0; v < 8; ++v)
      #pragma unroll
      for (int r = 0; r < 4; ++r) O[v][r] *= alO[r];

    // ---- P@V: 16 MFMA, A-frag = lane's own S (permuted valF) ----
    #pragma unroll
    for (int ks2 = 0; ks2 < 2; ++ks2) {
      h8v a;
      #pragma unroll
      for (int e = 0; e < 4; ++e) {
        a[e]     = (_Float16)S[2 * ks2][e];
        a[e + 4] = (_Float16)S[2 * ks2 + 1][e];
      }
      #pragma unroll
      for (int v = 0; v < 8; ++v) {
        h8v b = *(const h8v*)(Vc + (size_t)(v * 2 + ks2) * 512 + lane * 8);
        O[v] = MFMA16(a, b, O[v]);
      }
    }

    // drain next-chunk staging + protect dbuf reuse across all 8 waves
    asm volatile("s_waitcnt vmcnt(0)" ::: "memory");
    __syncthreads();
  }

  // ---- final denominator: reduce over quads, redistribute to O layout ----
  rl += __shfl_xor(rl, 16); rl += __shfl_xor(rl, 32);
  float rlO[4];
  #pragma unroll
  for (int r = 0; r < 4; ++r) rlO[r] = __shfl(rl, quad * 4 + r);

  // reload stashed qf (qstash untouched by chunk staging), then barrier
  // before per-wave scratch (overlaps other waves' stash region).
  h8v qf0 = *(const h8v*)&qstash[0 * 512 + lane * 8];
  h8v qf1 = *(const h8v*)&qstash[1 * 512 + lane * 8];
  __syncthreads();

  // ================= phase 3: epilogue =================
  // retrieved -> LDS fp16
  #pragma unroll
  for (int v = 0; v < 8; ++v)
    #pragma unroll
    for (int r = 0; r < 4; ++r)
      P_s[(quad * 4 + r) * 136 + v * 16 + l15] = (_Float16)(O[v][r] / rlO[r]);

  // contiguous nt stores: 8 iters x (64 lanes x 16 B)
  #pragma unroll
  for (int it = 0; it < 8; ++it) {
    int flat = it * 256 + lane * 4;
    int row = flat >> 7, col = flat & 127;
    h4v t = *(const h4v*)&P_s[row * 136 + col];
    f4v o;
    o.x = (float)t[0]; o.y = (float)t[1]; o.z = (float)t[2]; o.w = (float)t[3];
    __builtin_nontemporal_store(o, (f4v*)(out_ret + (size_t)q0 * VAL + flat));
  }

  // c1: relu([qf|ret] @ c1_W + b); b-frags straight from L2 (one-shot)
  {
    f4v H[8];
    #pragma unroll
    for (int f = 0; f < 8; ++f) H[f] = fz;
    #pragma unroll
    for (int ks = 0; ks < 6; ++ks) {
      const int k0 = ks * 32;
      h8v a = (ks == 0) ? qf0 : (ks == 1) ? qf1
               : *(const h8v*)&P_s[l15 * 136 + (k0 - 64) + quad * 8];
      #pragma unroll
      for (int f = 0; f < 8; ++f) {
        h8v b = *(const h8v*)(c1F + (size_t)(f * 6 + ks) * 512 + lane * 8);
        H[f] = MFMA16(a, b, H[f]);
      }
    }
    #pragma unroll
    for (int f = 0; f < 8; ++f) {
      float bb = c1_b[f * 16 + l15];
      #pragma unroll
      for (int r = 0; r < 4; ++r)
        P_s[(quad * 4 + r) * 136 + f * 16 + l15] =
            (_Float16)fmaxf(0.f, H[f][r] + bb);
    }
  }

  // c2: relu(h1 @ c2_W + b) -> h2
  {
    f4v G[4];
    #pragma unroll
    for (int f = 0; f < 4; ++f) G[f] = fz;
    #pragma unroll
    for (int ks = 0; ks < 4; ++ks) {
      h8v a = *(const h8v*)&P_s[l15 * 136 + ks * 32 + quad * 8];
      #pragma unroll
      for (int f = 0; f < 4; ++f) {
        h8v b = *(const h8v*)(c2F + (size_t)(f * 4 + ks) * 512 + lane * 8);
        G[f] = MFMA16(a, b, G[f]);
      }
    }
    #pragma unroll
    for (int f = 0; f < 4; ++f) {
      float bb = c2_b[f * 16 + l15];
      #pragma unroll
      for (int r = 0; r < 4; ++r)
        h2_s[(quad * 4 + r) * 72 + f * 16 + l15] =
            (_Float16)fmaxf(0.f, G[f][r] + bb);
    }
  }

  // c3 + loss (4 lanes per query row)
  float lsum;
  {
    const int prow = lane >> 2, pj = lane & 3;
    float s = 0.f;
    #pragma unroll
    for (int k = 0; k < 16; ++k) {
      int kk = pj * 16 + k;
      s += (float)h2_s[prow * 72 + kk] * c3W[kk];
    }
    s += __shfl_xor(s, 1);
    s += __shfl_xor(s, 2);
    float pred = s + c3b[0];
    float diff = pred - qy[q0 + prow];
    if (pj == 0) out_pred[q0 + prow] = pred;
    lsum = diff * diff;                        // each row counted 4x
  }
  #pragma unroll
  for (int m = 1; m < 64; m <<= 1) lsum += __shfl_xor(lsum, m);
  if (lane == 0) atomicAdd(dout, lsum * (1.0f / (4.0f * (float)BQ)));
}

// ---------------------------------------------------------------------------
extern "C" void kernel_launch(void* const* d_in, const int* in_sizes, int n_in,
                              void* d_out, int out_size, void* d_ws, size_t ws_size,
                              hipStream_t stream)
{
  const float* support_x = (const float*)d_in[0];
  const float* support_y = (const float*)d_in[1];
  const float* query_x   = (const float*)d_in[2];
  const float* query_y   = (const float*)d_in[3];
  const float* base_W    = (const float*)d_in[4];
  const float* base_b    = (const float*)d_in[5];
  const float* kp_W      = (const float*)d_in[6];
  const float* kp_b      = (const float*)d_in[7];
  const float* vp_W      = (const float*)d_in[8];
  const float* vp_b      = (const float*)d_in[9];
  const float* mem_keys  = (const float*)d_in[10];
  const float* mem_vals  = (const float*)d_in[11];
  const float* mem_age   = (const float*)d_in[12];
  const float* c1_W      = (const float*)d_in[13];
  const float* c1_b      = (const float*)d_in[14];
  const float* c2_W      = (const float*)d_in[15];
  const float* c2_b      = (const float*)d_in[16];
  const float* c3_W      = (const float*)d_in[17];
  const float* c3_b      = (const float*)d_in[18];

  char* w = (char*)d_ws;                        // ~1 MB used
  _Float16* WTf   = (_Float16*)(w + 0);         // 128 KB fragment-major
  _Float16* vpWt  = (_Float16*)(w + 131072);    // 32 KB
  _Float16* c1F   = (_Float16*)(w + 163840);    // 48 KB fragment-major
  _Float16* c2F   = (_Float16*)(w + 212992);    // 16 KB fragment-major
  float*    bcomb = (float*)   (w + 229376);    // 512 B
  int*      ranks = (int*)     (w + 229888);    // 4 KB
  float*    pkeys = (float*)   (w + 233984);    // 128 KB
  float*    pvals = (float*)   (w + 365056);    // 256 KB
  _Float16* keysF = (_Float16*)(w + 627200);    // 128 KB fragment-major
  _Float16* valF  = (_Float16*)(w + 758272);    // 256 KB fragment-major

  float* out = (float*)d_out;

  hipLaunchKernelGGL(k_prep1, dim3(453), dim3(256), 0, stream,
                     base_W, base_b, kp_W, kp_b, vp_W, c1_W, c2_W, mem_age,
                     WTf, bcomb, vpWt, c1F, c2F, ranks, out);
  hipLaunchKernelGGL(k_prep2, dim3(64), dim3(64), 0, stream,
                     support_x, support_y, WTf, bcomb, vpWt, vp_b, pkeys, pvals);
  hipLaunchKernelGGL(k_prep3, dim3(768), dim3(256), 0, stream,
                     ranks, pkeys, pvals, mem_keys, mem_vals, keysF, valF);
  hipLaunchKernelGGL(k_fused, dim3(BQ / 128), dim3(512), 0, stream,
                     query_x, query_y, WTf, bcomb, c1_b, c2_b, c3_W, c3_b,
                     c1F, c2F, keysF, valF, out);
}

// Round 10
// 364.425 us; speedup vs baseline: 1.0160x; 1.0160x over previous
//
#include <hip/hip_runtime.h>

typedef _Float16 h8v __attribute__((ext_vector_type(8)));
typedef _Float16 h4v __attribute__((ext_vector_type(4)));
typedef float    f4v __attribute__((ext_vector_type(4)));

#define MFMA16(a,b,c) __builtin_amdgcn_mfma_f32_16x16x32_f16((a),(b),(c),0,0,0)
#define NEGF (-1e30f)

#define MEM 1000
#define KEY 64
#define VAL 128
#define DIN 512
#define BS  512
#define BQ  65536
#define NCOPY 8

// Fragment-major B layouts: element (F,KS,lane,j) at ((F*nKS+KS)*64+lane)*8+j
// holds B[n = F*16 + (lane&15)][k = KS*32 + (lane>>4)*8 + j].
//
// SWAPPED-QK (verified R5): MFMA16(Kfrag, Qfrag) computes P^T with
// P[query=lane&15][slot = f*16 + quad*4 + r] lane-local; valF's k-dim is
// permuted in prep3 so PV's A-frag is the lane's OWN S values.
//
// R9 (convoy theory): R7 vs R8 showed a FIXED ~8 us per chunk-iteration
// regardless of chunk size / occupancy / MFMA count -> same-address
// queueing: all 512 blocks stage the SAME K/V lines at the same relative
// time; vmcnt(0)+barrier waits for the slowest request of the storm.
// Fixes: (1) 8 copies of keysF/valF/WTf/c1F/c2F, block uses copy
// blockIdx&7; (2) per-block chunk-order rotation (online softmax is
// order-independent); (3) exact defer-rescale.
// R10 = R9 repaired: (a) pvals workspace offset overlapped pkeys by 512 B
// (deterministic corruption, absmax 46.6); (b) R8/R9's c==15 c1F staging
// wrote 48 KB over the LIVE K1/V1 buffers (won the race by luck) -> now
// the epilogue reads c1F directly from L2 (per-block copy, MFMA-hidden).

typedef __attribute__((address_space(1))) const unsigned int guint;
typedef __attribute__((address_space(3))) unsigned int luint;

// async global->LDS, 16 B/lane: LDS gets [uniform l + lane*16B] = g[lane*16B]
__device__ __forceinline__ void gld16(const _Float16* g, _Float16* l)
{
  __builtin_amdgcn_global_load_lds((guint*)g, (luint*)l, 16, 0, 0);
}

__device__ __forceinline__ h8v cvt8(const float* p)
{
  f4v u = *(const f4v*)p;
  f4v v = *(const f4v*)(p + 4);
  h8v a;
  a[0] = (_Float16)u.x; a[1] = (_Float16)u.y; a[2] = (_Float16)u.z; a[3] = (_Float16)u.w;
  a[4] = (_Float16)v.x; a[5] = (_Float16)v.y; a[6] = (_Float16)v.z; a[7] = (_Float16)v.w;
  return a;
}

__device__ __forceinline__ h8v cvt8nt(const float* p)
{
  f4v u = __builtin_nontemporal_load((const f4v*)p);
  f4v v = __builtin_nontemporal_load((const f4v*)(p + 4));
  h8v a;
  a[0] = (_Float16)u.x; a[1] = (_Float16)u.y; a[2] = (_Float16)u.z; a[3] = (_Float16)u.w;
  a[4] = (_Float16)v.x; a[5] = (_Float16)v.y; a[6] = (_Float16)v.z; a[7] = (_Float16)v.w;
  return a;
}

// ---------------------------------------------------------------------------
// prep1: fragment-major weights (copy 0), Wck fused, bcomb, ranks, zero
// ---------------------------------------------------------------------------
__global__ void k_prep1(const float* __restrict__ baseW, const float* __restrict__ base_b,
                        const float* __restrict__ kpW, const float* __restrict__ kp_b,
                        const float* __restrict__ vpW, const float* __restrict__ c1W,
                        const float* __restrict__ c2W, const float* __restrict__ age,
                        _Float16* __restrict__ WTf, float* __restrict__ bcomb,
                        _Float16* __restrict__ vpWt, _Float16* __restrict__ c1F,
                        _Float16* __restrict__ c2F, int* __restrict__ ranks,
                        float* __restrict__ out0)
{
  long id = (long)blockIdx.x * 256 + threadIdx.x;
  if (id < 65536) {                        // WTf: [baseW^T | Wck^T], n=128, k=512 (KS=16)
    int h = (int)id;
    int j = h & 7, lane = (h >> 3) & 63, KS = (h >> 9) & 15, F = h >> 13;
    int n = F * 16 + (lane & 15);
    int k = KS * 32 + ((lane >> 4) << 3) + j;
    float v;
    if (n < 64) v = baseW[(size_t)k * 64 + n];
    else {
      int nn = n - 64;
      const float* br = baseW + (size_t)k * 64;
      float s = 0.f;
      for (int t = 0; t < 64; ++t) s += br[t] * kpW[t * 64 + nn];
      v = s;
    }
    WTf[h] = (_Float16)v;
  } else if (id < 65664) {                 // bcomb
    int i = (int)(id - 65536);
    if (i < 64) bcomb[i] = base_b[i];
    else {
      int n = i - 64;
      float s = kp_b[n];
      for (int t = 0; t < 64; ++t) s += base_b[t] * kpW[t * 64 + n];
      bcomb[i] = s;
    }
  } else if (id < 90240) {                 // c1F: n=128 (F=8), k=192 (KS=6)
    int h = (int)(id - 65664);
    int j = h & 7, lane = (h >> 3) & 63, KS = (h >> 9) % 6, F = (h >> 9) / 6;
    int n = F * 16 + (lane & 15);
    int k = KS * 32 + ((lane >> 4) << 3) + j;
    c1F[h] = (_Float16)c1W[(size_t)k * 128 + n];
  } else if (id < 98432) {                 // c2F: n=64 (F=4), k=128 (KS=4)
    int h = (int)(id - 90240);
    int j = h & 7, lane = (h >> 3) & 63, KS = (h >> 9) & 3, F = h >> 11;
    int n = F * 16 + (lane & 15);
    int k = KS * 32 + ((lane >> 4) << 3) + j;
    c2F[h] = (_Float16)c2W[(size_t)k * 64 + n];
  } else if (id < 114816) {                // vpWt[n][k] (row-major transposed, prep2 only)
    long i = id - 98432;
    int n = (int)(i >> 7), k = (int)(i & 127);
    vpWt[i] = (_Float16)vpW[(size_t)k * 128 + n];
  } else if (id < 115816) {                // stable ranks (lax.top_k order)
    int jx = (int)(id - 114816);
    float aj = age[jx];
    int r = 0;
    for (int i2 = 0; i2 < MEM; ++i2) {
      float ai = age[i2];
      r += (ai > aj) || (ai == aj && i2 < jx);
    }
    ranks[jx] = r;
  } else if (id == 115816) {
    *out0 = 0.f;
  }
}

// ---------------------------------------------------------------------------
// prep2: pkeys = sx@Wck + bck ; pvals = sy@vpW + vp_b  (uses copy-0 WTf)
// ---------------------------------------------------------------------------
__global__ __launch_bounds__(64) void k_prep2(
    const float* __restrict__ sx, const float* __restrict__ sy,
    const _Float16* __restrict__ WTf, const float* __restrict__ bcomb,
    const _Float16* __restrict__ vpWt, const float* __restrict__ vp_b,
    float* __restrict__ pkeys, float* __restrict__ pvals)
{
  const int lane = threadIdx.x, quad = lane >> 4, l15 = lane & 15;
  const f4v fz = {0.f, 0.f, 0.f, 0.f};
  if (blockIdx.x < 32) {
    const int m0 = blockIdx.x * 16;
    f4v acc[4];
    #pragma unroll
    for (int f = 0; f < 4; ++f) acc[f] = fz;
    const float* xr = sx + (size_t)(m0 + l15) * DIN;
    #pragma unroll 4
    for (int ks = 0; ks < 16; ++ks) {
      int k0 = ks * 32 + quad * 8;
      h8v a = cvt8(xr + k0);
      #pragma unroll
      for (int f = 0; f < 4; ++f) {
        h8v b = *(const h8v*)(WTf + (size_t)((((4 + f) * 16) + ks) * 64 + lane) * 8);
        acc[f] = MFMA16(a, b, acc[f]);
      }
    }
    #pragma unroll
    for (int f = 0; f < 4; ++f) {
      int col = f * 16 + l15;
      float bb = bcomb[64 + col];
      #pragma unroll
      for (int r = 0; r < 4; ++r)
        pkeys[(size_t)(m0 + quad * 4 + r) * KEY + col] = acc[f][r] + bb;
    }
  } else {
    const int m0 = (blockIdx.x - 32) * 16;
    f4v acc[8];
    #pragma unroll
    for (int f = 0; f < 8; ++f) acc[f] = fz;
    const float* yr = sy + (size_t)(m0 + l15) * VAL;
    #pragma unroll
    for (int ks = 0; ks < 4; ++ks) {
      int k0 = ks * 32 + quad * 8;
      h8v a = cvt8(yr + k0);
      #pragma unroll
      for (int f = 0; f < 8; ++f) {
        h8v b = *(const h8v*)(vpWt + (size_t)(f * 16 + l15) * 128 + k0);
        acc[f] = MFMA16(a, b, acc[f]);
      }
    }
    #pragma unroll
    for (int f = 0; f < 8; ++f) {
      int col = f * 16 + l15;
      float bb = vp_b[col];
      #pragma unroll
      for (int r = 0; r < 4; ++r)
        pvals[(size_t)(m0 + quad * 4 + r) * VAL + col] = acc[f][r] + bb;
    }
  }
}

// ---------------------------------------------------------------------------
// prep3: build 8 copies of keysF/valF (computed independently per copy) and
// replicate WTf/c1F/c2F copies 1..7 (copy 0 written by prep1).
// keysF: n=1024 slots (F=64), k=KEY 64 (KS=2)
// valF : n=VAL 128 (F=8), k=1024 slots (KS=32), k-dim permuted per 32-slot
//        step: frag pos (quad,j) holds slot KS*32 + (j>>2)*16 + quad*4 + (j&3)
// id space: 8*65536 keysF | 8*131072 valF | 7*65536 WTf | 7*24576 c1F | 7*8192 c2F
// total 2,260,992 -> grid 8832 x 256
// ---------------------------------------------------------------------------
__global__ void k_prep3(const int* __restrict__ ranks, const float* __restrict__ pk,
                        const float* __restrict__ pv, const float* __restrict__ memK,
                        const float* __restrict__ memV,
                        _Float16* __restrict__ keysF, _Float16* __restrict__ valF,
                        _Float16* __restrict__ WTf, _Float16* __restrict__ c1F,
                        _Float16* __restrict__ c2F)
{
  long id = (long)blockIdx.x * 256 + threadIdx.x;
  if (id < 8L * 65536) {                                   // keysF x8
    int h = (int)(id & 65535);
    int copy = (int)(id >> 16);
    int j = h & 7, lane = (h >> 3) & 63, KS = (h >> 9) & 1, F = h >> 10;
    int n = F * 16 + (lane & 15);                  // mem slot
    int k = KS * 32 + ((lane >> 4) << 3) + j;      // key col
    float v = 0.f;
    if (n < MEM) {
      int rk = ranks[n];
      v = (rk < BS) ? pk[(size_t)rk * KEY + k] : memK[(size_t)n * KEY + k];
    }
    keysF[(size_t)copy * 65536 + h] = (_Float16)v;
  } else if (id < 8L * 65536 + 8L * 131072) {              // valF x8
    long i = id - 8L * 65536;
    int h = (int)(i & 131071);
    int copy = (int)(i >> 17);
    int j = h & 7, lane = (h >> 3) & 63, KS = (h >> 9) & 31, F = h >> 14;
    int nv = F * 16 + (lane & 15);                 // val col
    int jm = KS * 32 + ((j >> 2) << 4) + ((lane >> 4) << 2) + (j & 3);
    float v = 0.f;
    if (jm < MEM) {
      int rk = ranks[jm];
      v = (rk < BS) ? pv[(size_t)rk * VAL + nv] : memV[(size_t)jm * VAL + nv];
    }
    valF[(size_t)copy * 131072 + h] = (_Float16)v;
  } else {
    long i = id - (8L * 65536 + 8L * 131072);
    if (i < 7L * 65536) {                                  // WTf copies 1..7
      int copy = 1 + (int)(i >> 16); int h = (int)(i & 65535);
      WTf[(size_t)copy * 65536 + h] = WTf[h];
    } else if ((i -= 7L * 65536) < 7L * 24576) {           // c1F copies 1..7
      int copy = 1 + (int)(i / 24576); int h = (int)(i % 24576);
      c1F[(size_t)copy * 24576 + h] = c1F[h];
    } else if ((i -= 7L * 24576) < 7L * 8192) {            // c2F copies 1..7
      int copy = 1 + (int)(i >> 13); int h = (int)(i & 8191);
      c2F[(size_t)copy * 8192 + h] = c2F[h];
    }
  }
}

// ---------------------------------------------------------------------------
// fused: features + attention + controller, 16 q/wave, 8 waves/block,
// grid 512, LDS 64 KB -> 2 blocks/CU. Per-block copy selection + chunk
// rotation decorrelate the shared-operand staging storms (R9 theory).
// Epilogue c1F read directly from L2 (no LDS staging -> no buffer race).
// ---------------------------------------------------------------------------
__global__ __launch_bounds__(512, 4) void k_fused(
    const float* __restrict__ qx, const float* __restrict__ qy,
    const _Float16* __restrict__ WTf_, const float* __restrict__ bcomb,
    const float* __restrict__ c1_b, const float* __restrict__ c2_b,
    const float* __restrict__ c3W, const float* __restrict__ c3b,
    const _Float16* __restrict__ c1F_, const _Float16* __restrict__ c2F_,
    const _Float16* __restrict__ keysF_, const _Float16* __restrict__ valF_,
    float* __restrict__ dout)
{
  __shared__ __align__(16) char smem[65536];
  // phase 1: Wq[0]=[0,32K), Wq[1]=[32K,64K)
  _Float16* const Wq0 = (_Float16*)smem;
  _Float16* const Wq1 = (_Float16*)(smem + 32768);
  // phase 2: K dbuf 2x8K at 0, V dbuf 2x16K at 16K, qf stash 16K at 48K
  _Float16* const K0 = (_Float16*)smem;                  // 4096 halves
  _Float16* const K1 = (_Float16*)(smem + 8192);
  _Float16* const V0 = (_Float16*)(smem + 16384);        // 8192 halves
  _Float16* const V1 = (_Float16*)(smem + 32768);

  const int tid  = threadIdx.x;
  const int wid  = tid >> 6;
  const int lane = tid & 63;
  const int quad = lane >> 4;
  const int l15  = lane & 15;

  // per-block decorrelators
  const int cpy  = blockIdx.x & 7;
  const int rot  = (blockIdx.x >> 3) & 15;     // phase-2 chunk rotation
  const int qrot = (blockIdx.x >> 1) & 3;      // phase-1 quarter rotation
  const _Float16* const WTf   = WTf_   + (size_t)cpy * 65536;
  const _Float16* const c1F   = c1F_   + (size_t)cpy * 24576;
  const _Float16* const c2F   = c2F_   + (size_t)cpy * 8192;
  const _Float16* const keysF = keysF_ + (size_t)cpy * 65536;
  const _Float16* const valF  = valF_  + (size_t)cpy * 131072;

  _Float16* const qstash = (_Float16*)(smem + 49152 + wid * 2048);  // 2x512 h
  // phase 3 per-wave scratch (dead K/V area): 2176 + 1152 halves
  _Float16* const P_s  = (_Float16*)(smem + wid * 6656);
  _Float16* const h2_s = P_s + 2176;

  const int tile = blockIdx.x * 8 + wid;       // one 16-query tile per wave
  const int q0   = tile * 16;

  float* out_pred = dout + 1;
  float* out_ret  = dout + 1 + BQ;
  const f4v fz = {0.f, 0.f, 0.f, 0.f};

  // ================= phase 1: features (dbuf 32 KB quarters, rotated) ====
  #pragma unroll
  for (int i = 0; i < 4; ++i) {                // stage quarter qrot -> Wq0
    const int t = wid * 4 + i;
    const int f = t >> 2, ksq = t & 3;
    gld16(WTf + (size_t)(f * 16 + qrot * 4 + ksq) * 512 + lane * 8, Wq0 + t * 512);
  }
  asm volatile("s_waitcnt vmcnt(0)" ::: "memory");
  __syncthreads();

  f4v acc[8];
  #pragma unroll
  for (int f = 0; f < 8; ++f) acc[f] = fz;
  const float* xr = qx + (size_t)(q0 + l15) * DIN;

  #pragma unroll
  for (int q = 0; q < 4; ++q) {
    const int qe = (q + qrot) & 3;             // processed quarter
    _Float16* const Wb = (q & 1) ? Wq1 : Wq0;
    _Float16* const Wn = (q & 1) ? Wq0 : Wq1;
    if (q < 3) {                               // stage next quarter
      const int qn = (q + 1 + qrot) & 3;
      #pragma unroll
      for (int i = 0; i < 4; ++i) {
        const int t = wid * 4 + i;
        const int f = t >> 2, ksq = t & 3;
        gld16(WTf + (size_t)(f * 16 + qn * 4 + ksq) * 512 + lane * 8,
              Wn + t * 512);
      }
    }
    #pragma unroll
    for (int ksq = 0; ksq < 4; ++ksq) {
      const int ks = qe * 4 + ksq;
      h8v a = cvt8nt(xr + ks * 32 + quad * 8);
      #pragma unroll
      for (int f = 0; f < 8; ++f) {
        h8v b = *(const h8v*)(Wb + (size_t)((f * 4 + ksq) * 64 + lane) * 8);
        acc[f] = MFMA16(a, b, acc[f]);
      }
    }
    asm volatile("s_waitcnt vmcnt(0)" ::: "memory");
    __syncthreads();
  }

  // C-layout -> A-frag registers via per-wave LDS transpose (Wq area dead).
  // qf frags go to the qstash (live through phase 2), pq stay in registers.
  _Float16* tbuf = (_Float16*)(smem + wid * 4352);  // 2176 halves
  h8v pq0, pq1;
  {
    #pragma unroll
    for (int f = 0; f < 8; ++f) {
      float bb = bcomb[f * 16 + l15];
      #pragma unroll
      for (int r = 0; r < 4; ++r)
        tbuf[(quad * 4 + r) * 136 + f * 16 + l15] = (_Float16)(acc[f][r] + bb);
    }
    h8v qf0 = *(const h8v*)&tbuf[l15 * 136 +  0 + quad * 8];
    h8v qf1 = *(const h8v*)&tbuf[l15 * 136 + 32 + quad * 8];
    pq0 = *(const h8v*)&tbuf[l15 * 136 + 64 + quad * 8];
    pq1 = *(const h8v*)&tbuf[l15 * 136 + 96 + quad * 8];
    *(h8v*)&qstash[0 * 512 + lane * 8] = qf0;
    *(h8v*)&qstash[1 * 512 + lane * 8] = qf1;
  }
  __syncthreads();   // tbuf reads done -> K/V staging may overwrite [0,48K)

  // ================= phase 2: attention (16 chunks of 64 slots, rotated) =
  // chunk ce: K tiles keysF[(ce*8+i)*512] -> Kbuf + i*512
  //           V tiles valF[(v*32 + ce*2 + ks2)*512] -> Vbuf + (v*2+ks2)*512
  #pragma unroll
  for (int i = 0; i < 3; ++i) {                // stage chunk `rot`
    const int t = wid * 3 + i;
    if (t < 8) gld16(keysF + (size_t)(rot * 8 + t) * 512 + lane * 8, K0 + t * 512);
    else {
      const int tv = t - 8;
      gld16(valF + (size_t)((tv >> 1) * 32 + rot * 2 + (tv & 1)) * 512 + lane * 8,
            V0 + tv * 512);
    }
  }
  asm volatile("s_waitcnt vmcnt(0)" ::: "memory");
  __syncthreads();

  float rm = NEGF, rl = 0.f;                   // scalars (query = l15)
  f4v O[8];
  #pragma unroll
  for (int v = 0; v < 8; ++v) O[v] = fz;

  #pragma unroll 1
  for (int c = 0; c < 16; ++c) {
    const int ce  = (c + rot) & 15;            // processed chunk
    const int cur = c & 1;
    _Float16* const Kc = cur ? K1 : K0;
    _Float16* const Vc = cur ? V1 : V0;
    _Float16* const Kn = cur ? K0 : K1;
    _Float16* const Vn = cur ? V0 : V1;

    if (c < 15) {                              // prefetch next chunk
      const int ne = (c + 1 + rot) & 15;
      #pragma unroll
      for (int i = 0; i < 3; ++i) {
        const int t = wid * 3 + i;
        if (t < 8)
          gld16(keysF + (size_t)(ne * 8 + t) * 512 + lane * 8, Kn + t * 512);
        else {
          const int tv = t - 8;
          gld16(valF + (size_t)((tv >> 1) * 32 + ne * 2 + (tv & 1)) * 512 + lane * 8,
                Vn + tv * 512);
        }
      }
    }

    // ---- QK^T (swapped): 8 MFMA, S lane-local ----
    f4v S[4];
    #pragma unroll
    for (int f = 0; f < 4; ++f) S[f] = fz;
    #pragma unroll
    for (int f = 0; f < 4; ++f) {
      h8v b0 = *(const h8v*)(Kc + (size_t)(f * 2 + 0) * 512 + lane * 8);
      h8v b1 = *(const h8v*)(Kc + (size_t)(f * 2 + 1) * 512 + lane * 8);
      S[f] = MFMA16(b0, pq0, S[f]);
      S[f] = MFMA16(b1, pq1, S[f]);
    }

    // ---- register softmax (16 vals/lane), defer-rescale (exact skip) ----
    float cm = NEGF;
    #pragma unroll
    for (int f = 0; f < 4; ++f) {
      const int sb = ce * 64 + f * 16 + quad * 4;
      #pragma unroll
      for (int r = 0; r < 4; ++r) {
        float s = (sb + r < MEM) ? S[f][r] : NEGF;
        S[f][r] = s;
        cm = fmaxf(cm, s);
      }
    }
    cm = fmaxf(cm, __shfl_xor(cm, 16));
    cm = fmaxf(cm, __shfl_xor(cm, 32));
    if (__any(cm > rm)) {                      // skipped path is bitwise
      float mn = fmaxf(rm, cm);                // identical (al would be 1.0)
      float al = __expf(rm - mn);
      rm = mn;
      float alO[4];
      #pragma unroll
      for (int r = 0; r < 4; ++r) alO[r] = __shfl(al, quad * 4 + r);
      #pragma unroll
      for (int v = 0; v < 8; ++v)
        #pragma unroll
        for (int r = 0; r < 4; ++r) O[v][r] *= alO[r];
      rl *= al;
    }
    float psl = 0.f;
    #pragma unroll
    for (int f = 0; f < 4; ++f)
      #pragma unroll
      for (int r = 0; r < 4; ++r) {
        float p = __expf(S[f][r] - rm);
        S[f][r] = p;
        psl += p;
      }
    rl += psl;

    // ---- P@V: 16 MFMA, A-frag = lane's own S (permuted valF) ----
    #pragma unroll
    for (int ks2 = 0; ks2 < 2; ++ks2) {
      h8v a;
      #pragma unroll
      for (int e = 0; e < 4; ++e) {
        a[e]     = (_Float16)S[2 * ks2][e];
        a[e + 4] = (_Float16)S[2 * ks2 + 1][e];
      }
      #pragma unroll
      for (int v = 0; v < 8; ++v) {
        h8v b = *(const h8v*)(Vc + (size_t)(v * 2 + ks2) * 512 + lane * 8);
        O[v] = MFMA16(a, b, O[v]);
      }
    }

    // drain next-chunk staging + protect dbuf reuse across all 8 waves
    asm volatile("s_waitcnt vmcnt(0)" ::: "memory");
    __syncthreads();
  }

  // ---- final denominator: reduce over quads, redistribute to O layout ----
  rl += __shfl_xor(rl, 16); rl += __shfl_xor(rl, 32);
  float rlO[4];
  #pragma unroll
  for (int r = 0; r < 4; ++r) rlO[r] = __shfl(rl, quad * 4 + r);

  // reload stashed qf (qstash untouched by chunk staging), then barrier
  // before per-wave scratch (overlaps other waves' stash region).
  h8v qf0 = *(const h8v*)&qstash[0 * 512 + lane * 8];
  h8v qf1 = *(const h8v*)&qstash[1 * 512 + lane * 8];
  __syncthreads();

  // ================= phase 3: epilogue =================
  // retrieved -> LDS fp16
  #pragma unroll
  for (int v = 0; v < 8; ++v)
    #pragma unroll
    for (int r = 0; r < 4; ++r)
      P_s[(quad * 4 + r) * 136 + v * 16 + l15] = (_Float16)(O[v][r] / rlO[r]);

  // contiguous nt stores: 8 iters x (64 lanes x 16 B)
  #pragma unroll
  for (int it = 0; it < 8; ++it) {
    int flat = it * 256 + lane * 4;
    int row = flat >> 7, col = flat & 127;
    h4v t = *(const h4v*)&P_s[row * 136 + col];
    f4v o;
    o.x = (float)t[0]; o.y = (float)t[1]; o.z = (float)t[2]; o.w = (float)t[3];
    __builtin_nontemporal_store(o, (f4v*)(out_ret + (size_t)q0 * VAL + flat));
  }

  // c1: relu([qf|ret] @ c1_W + b); b-frags directly from L2 (per-block copy)
  {
    f4v H[8];
    #pragma unroll
    for (int f = 0; f < 8; ++f) H[f] = fz;
    #pragma unroll
    for (int ks = 0; ks < 6; ++ks) {
      const int k0 = ks * 32;
      h8v a = (ks == 0) ? qf0 : (ks == 1) ? qf1
               : *(const h8v*)&P_s[l15 * 136 + (k0 - 64) + quad * 8];
      #pragma unroll
      for (int f = 0; f < 8; ++f) {
        h8v b = *(const h8v*)(c1F + (size_t)(f * 6 + ks) * 512 + lane * 8);
        H[f] = MFMA16(a, b, H[f]);
      }
    }
    #pragma unroll
    for (int f = 0; f < 8; ++f) {
      float bb = c1_b[f * 16 + l15];
      #pragma unroll
      for (int r = 0; r < 4; ++r)
        P_s[(quad * 4 + r) * 136 + f * 16 + l15] =
            (_Float16)fmaxf(0.f, H[f][r] + bb);
    }
  }

  // c2: relu(h1 @ c2_W + b) -> h2
  {
    f4v G[4];
    #pragma unroll
    for (int f = 0; f < 4; ++f) G[f] = fz;
    #pragma unroll
    for (int ks = 0; ks < 4; ++ks) {
      h8v a = *(const h8v*)&P_s[l15 * 136 + ks * 32 + quad * 8];
      #pragma unroll
      for (int f = 0; f < 4; ++f) {
        h8v b = *(const h8v*)(c2F + (size_t)(f * 4 + ks) * 512 + lane * 8);
        G[f] = MFMA16(a, b, G[f]);
      }
    }
    #pragma unroll
    for (int f = 0; f < 4; ++f) {
      float bb = c2_b[f * 16 + l15];
      #pragma unroll
      for (int r = 0; r < 4; ++r)
        h2_s[(quad * 4 + r) * 72 + f * 16 + l15] =
            (_Float16)fmaxf(0.f, G[f][r] + bb);
    }
  }

  // c3 + loss (4 lanes per query row)
  float lsum;
  {
    const int prow = lane >> 2, pj = lane & 3;
    float s = 0.f;
    #pragma unroll
    for (int k = 0; k < 16; ++k) {
      int kk = pj * 16 + k;
      s += (float)h2_s[prow * 72 + kk] * c3W[kk];
    }
    s += __shfl_xor(s, 1);
    s += __shfl_xor(s, 2);
    float pred = s + c3b[0];
    float diff = pred - qy[q0 + prow];
    if (pj == 0) out_pred[q0 + prow] = pred;
    lsum = diff * diff;                        // each row counted 4x
  }
  #pragma unroll
  for (int m = 1; m < 64; m <<= 1) lsum += __shfl_xor(lsum, m);
  if (lane == 0) atomicAdd(dout, lsum * (1.0f / (4.0f * (float)BQ)));
}

// ---------------------------------------------------------------------------
extern "C" void kernel_launch(void* const* d_in, const int* in_sizes, int n_in,
                              void* d_out, int out_size, void* d_ws, size_t ws_size,
                              hipStream_t stream)
{
  const float* support_x = (const float*)d_in[0];
  const float* support_y = (const float*)d_in[1];
  const float* query_x   = (const float*)d_in[2];
  const float* query_y   = (const float*)d_in[3];
  const float* base_W    = (const float*)d_in[4];
  const float* base_b    = (const float*)d_in[5];
  const float* kp_W      = (const float*)d_in[6];
  const float* kp_b      = (const float*)d_in[7];
  const float* vp_W      = (const float*)d_in[8];
  const float* vp_b      = (const float*)d_in[9];
  const float* mem_keys  = (const float*)d_in[10];
  const float* mem_vals  = (const float*)d_in[11];
  const float* mem_age   = (const float*)d_in[12];
  const float* c1_W      = (const float*)d_in[13];
  const float* c1_b      = (const float*)d_in[14];
  const float* c2_W      = (const float*)d_in[15];
  const float* c2_b      = (const float*)d_in[16];
  const float* c3_W      = (const float*)d_in[17];
  const float* c3_b      = (const float*)d_in[18];

  char* w = (char*)d_ws;                        // ~5.2 MB used
  _Float16* WTf   = (_Float16*)(w + 0);         // 8 x 128 KB (copies), ends 1048576
  _Float16* c1F   = (_Float16*)(w + 1048576);   // 8 x 48 KB, ends 1441792
  _Float16* c2F   = (_Float16*)(w + 1441792);   // 8 x 16 KB, ends 1572864
  _Float16* keysF = (_Float16*)(w + 1572864);   // 8 x 128 KB, ends 2621440
  _Float16* valF  = (_Float16*)(w + 2621440);   // 8 x 256 KB, ends 4718592
  _Float16* vpWt  = (_Float16*)(w + 4718592);   // 32 KB, ends 4751360
  float*    bcomb = (float*)   (w + 4751360);   // 512 B, ends 4751872
  int*      ranks = (int*)     (w + 4751872);   // 4 KB, ends 4755968
  float*    pkeys = (float*)   (w + 4755968);   // 128 KB, ends 4887040
  float*    pvals = (float*)   (w + 4887040);   // 256 KB, ends 5149184 (R9 bug:
                                                // was 4886528 -> overlapped pkeys)

  float* out = (float*)d_out;

  hipLaunchKernelGGL(k_prep1, dim3(453), dim3(256), 0, stream,
                     base_W, base_b, kp_W, kp_b, vp_W, c1_W, c2_W, mem_age,
                     WTf, bcomb, vpWt, c1F, c2F, ranks, out);
  hipLaunchKernelGGL(k_prep2, dim3(64), dim3(64), 0, stream,
                     support_x, support_y, WTf, bcomb, vpWt, vp_b, pkeys, pvals);
  hipLaunchKernelGGL(k_prep3, dim3(8832), dim3(256), 0, stream,
                     ranks, pkeys, pvals, mem_keys, mem_vals, keysF, valF,
                     WTf, c1F, c2F);
  hipLaunchKernelGGL(k_fused, dim3(BQ / 128), dim3(512), 0, stream,
                     query_x, query_y, WTf, bcomb, c1_b, c2_b, c3_W, c3_b,
                     c1F, c2F, keysF, valF, out);
}

// Round 11
// 362.605 us; speedup vs baseline: 1.0211x; 1.0050x over previous
//
#include <hip/hip_runtime.h>

typedef _Float16 h8v __attribute__((ext_vector_type(8)));
typedef _Float16 h4v __attribute__((ext_vector_type(4)));
typedef float    f4v __attribute__((ext_vector_type(4)));

#define MFMA16(a,b,c) __builtin_amdgcn_mfma_f32_16x16x32_f16((a),(b),(c),0,0,0)
#define NEGF (-1e30f)

#define MEM 1000
#define KEY 64
#define VAL 128
#define DIN 512
#define BS  512
#define BQ  65536
#define NCOPY 8

// Fragment-major B layouts: element (F,KS,lane,j) at ((F*nKS+KS)*64+lane)*8+j
// holds B[n = F*16 + (lane&15)][k = KS*32 + (lane>>4)*8 + j].
//
// SWAPPED-QK (verified R5): MFMA16(Kfrag, Qfrag) computes P^T with
// P[query=lane&15][slot = f*16 + quad*4 + r] lane-local; valF's k-dim is
// permuted in prep3 so PV's A-frag is the lane's OWN S values.
//
// R11 (counted-vmcnt pipeline): R7/R8/R10 all show an invariant ~6-7.5 us
// per chunk-beat; decorrelation (R10) only moved 131->120. The one constant
// across all: every iteration drains vmcnt to 0 before the barrier, giving
// loads <1 chunk-period to land and publishing the slowest wave's latency
// to all 8 waves, 16x per block. Fix per T3/T4: TRIPLE-buffer K/V, issue
// chunk c+2's loads at iter c, wait only vmcnt(3) at the bottom (vmcnt(0)
// solely at c==14). Loads now have 2 chunk-periods + 2 barriers to land.
// qf frags move LDS->registers (VGPR headroom exists at 64); LDS 72 KB
// keeps 2 blocks/CU.

typedef __attribute__((address_space(1))) const unsigned int guint;
typedef __attribute__((address_space(3))) unsigned int luint;

// async global->LDS, 16 B/lane: LDS gets [uniform l + lane*16B] = g[lane*16B]
__device__ __forceinline__ void gld16(const _Float16* g, _Float16* l)
{
  __builtin_amdgcn_global_load_lds((guint*)g, (luint*)l, 16, 0, 0);
}

__device__ __forceinline__ h8v cvt8(const float* p)
{
  f4v u = *(const f4v*)p;
  f4v v = *(const f4v*)(p + 4);
  h8v a;
  a[0] = (_Float16)u.x; a[1] = (_Float16)u.y; a[2] = (_Float16)u.z; a[3] = (_Float16)u.w;
  a[4] = (_Float16)v.x; a[5] = (_Float16)v.y; a[6] = (_Float16)v.z; a[7] = (_Float16)v.w;
  return a;
}

__device__ __forceinline__ h8v cvt8nt(const float* p)
{
  f4v u = __builtin_nontemporal_load((const f4v*)p);
  f4v v = __builtin_nontemporal_load((const f4v*)(p + 4));
  h8v a;
  a[0] = (_Float16)u.x; a[1] = (_Float16)u.y; a[2] = (_Float16)u.z; a[3] = (_Float16)u.w;
  a[4] = (_Float16)v.x; a[5] = (_Float16)v.y; a[6] = (_Float16)v.z; a[7] = (_Float16)v.w;
  return a;
}

// ---------------------------------------------------------------------------
// prep1: fragment-major weights (copy 0), Wck fused, bcomb, ranks, zero
// ---------------------------------------------------------------------------
__global__ void k_prep1(const float* __restrict__ baseW, const float* __restrict__ base_b,
                        const float* __restrict__ kpW, const float* __restrict__ kp_b,
                        const float* __restrict__ vpW, const float* __restrict__ c1W,
                        const float* __restrict__ c2W, const float* __restrict__ age,
                        _Float16* __restrict__ WTf, float* __restrict__ bcomb,
                        _Float16* __restrict__ vpWt, _Float16* __restrict__ c1F,
                        _Float16* __restrict__ c2F, int* __restrict__ ranks,
                        float* __restrict__ out0)
{
  long id = (long)blockIdx.x * 256 + threadIdx.x;
  if (id < 65536) {                        // WTf: [baseW^T | Wck^T], n=128, k=512 (KS=16)
    int h = (int)id;
    int j = h & 7, lane = (h >> 3) & 63, KS = (h >> 9) & 15, F = h >> 13;
    int n = F * 16 + (lane & 15);
    int k = KS * 32 + ((lane >> 4) << 3) + j;
    float v;
    if (n < 64) v = baseW[(size_t)k * 64 + n];
    else {
      int nn = n - 64;
      const float* br = baseW + (size_t)k * 64;
      float s = 0.f;
      for (int t = 0; t < 64; ++t) s += br[t] * kpW[t * 64 + nn];
      v = s;
    }
    WTf[h] = (_Float16)v;
  } else if (id < 65664) {                 // bcomb
    int i = (int)(id - 65536);
    if (i < 64) bcomb[i] = base_b[i];
    else {
      int n = i - 64;
      float s = kp_b[n];
      for (int t = 0; t < 64; ++t) s += base_b[t] * kpW[t * 64 + n];
      bcomb[i] = s;
    }
  } else if (id < 90240) {                 // c1F: n=128 (F=8), k=192 (KS=6)
    int h = (int)(id - 65664);
    int j = h & 7, lane = (h >> 3) & 63, KS = (h >> 9) % 6, F = (h >> 9) / 6;
    int n = F * 16 + (lane & 15);
    int k = KS * 32 + ((lane >> 4) << 3) + j;
    c1F[h] = (_Float16)c1W[(size_t)k * 128 + n];
  } else if (id < 98432) {                 // c2F: n=64 (F=4), k=128 (KS=4)
    int h = (int)(id - 90240);
    int j = h & 7, lane = (h >> 3) & 63, KS = (h >> 9) & 3, F = h >> 11;
    int n = F * 16 + (lane & 15);
    int k = KS * 32 + ((lane >> 4) << 3) + j;
    c2F[h] = (_Float16)c2W[(size_t)k * 64 + n];
  } else if (id < 114816) {                // vpWt[n][k] (row-major transposed, prep2 only)
    long i = id - 98432;
    int n = (int)(i >> 7), k = (int)(i & 127);
    vpWt[i] = (_Float16)vpW[(size_t)k * 128 + n];
  } else if (id < 115816) {                // stable ranks (lax.top_k order)
    int jx = (int)(id - 114816);
    float aj = age[jx];
    int r = 0;
    for (int i2 = 0; i2 < MEM; ++i2) {
      float ai = age[i2];
      r += (ai > aj) || (ai == aj && i2 < jx);
    }
    ranks[jx] = r;
  } else if (id == 115816) {
    *out0 = 0.f;
  }
}

// ---------------------------------------------------------------------------
// prep2: pkeys = sx@Wck + bck ; pvals = sy@vpW + vp_b  (uses copy-0 WTf)
// ---------------------------------------------------------------------------
__global__ __launch_bounds__(64) void k_prep2(
    const float* __restrict__ sx, const float* __restrict__ sy,
    const _Float16* __restrict__ WTf, const float* __restrict__ bcomb,
    const _Float16* __restrict__ vpWt, const float* __restrict__ vp_b,
    float* __restrict__ pkeys, float* __restrict__ pvals)
{
  const int lane = threadIdx.x, quad = lane >> 4, l15 = lane & 15;
  const f4v fz = {0.f, 0.f, 0.f, 0.f};
  if (blockIdx.x < 32) {
    const int m0 = blockIdx.x * 16;
    f4v acc[4];
    #pragma unroll
    for (int f = 0; f < 4; ++f) acc[f] = fz;
    const float* xr = sx + (size_t)(m0 + l15) * DIN;
    #pragma unroll 4
    for (int ks = 0; ks < 16; ++ks) {
      int k0 = ks * 32 + quad * 8;
      h8v a = cvt8(xr + k0);
      #pragma unroll
      for (int f = 0; f < 4; ++f) {
        h8v b = *(const h8v*)(WTf + (size_t)((((4 + f) * 16) + ks) * 64 + lane) * 8);
        acc[f] = MFMA16(a, b, acc[f]);
      }
    }
    #pragma unroll
    for (int f = 0; f < 4; ++f) {
      int col = f * 16 + l15;
      float bb = bcomb[64 + col];
      #pragma unroll
      for (int r = 0; r < 4; ++r)
        pkeys[(size_t)(m0 + quad * 4 + r) * KEY + col] = acc[f][r] + bb;
    }
  } else {
    const int m0 = (blockIdx.x - 32) * 16;
    f4v acc[8];
    #pragma unroll
    for (int f = 0; f < 8; ++f) acc[f] = fz;
    const float* yr = sy + (size_t)(m0 + l15) * VAL;
    #pragma unroll
    for (int ks = 0; ks < 4; ++ks) {
      int k0 = ks * 32 + quad * 8;
      h8v a = cvt8(yr + k0);
      #pragma unroll
      for (int f = 0; f < 8; ++f) {
        h8v b = *(const h8v*)(vpWt + (size_t)(f * 16 + l15) * 128 + k0);
        acc[f] = MFMA16(a, b, acc[f]);
      }
    }
    #pragma unroll
    for (int f = 0; f < 8; ++f) {
      int col = f * 16 + l15;
      float bb = vp_b[col];
      #pragma unroll
      for (int r = 0; r < 4; ++r)
        pvals[(size_t)(m0 + quad * 4 + r) * VAL + col] = acc[f][r] + bb;
    }
  }
}

// ---------------------------------------------------------------------------
// prep3: build 8 copies of keysF/valF and replicate WTf/c1F/c2F copies 1..7.
// keysF: n=1024 slots (F=64), k=KEY 64 (KS=2)
// valF : n=VAL 128 (F=8), k=1024 slots (KS=32), k-dim permuted per 32-slot
//        step: frag pos (quad,j) holds slot KS*32 + (j>>2)*16 + quad*4 + (j&3)
// ---------------------------------------------------------------------------
__global__ void k_prep3(const int* __restrict__ ranks, const float* __restrict__ pk,
                        const float* __restrict__ pv, const float* __restrict__ memK,
                        const float* __restrict__ memV,
                        _Float16* __restrict__ keysF, _Float16* __restrict__ valF,
                        _Float16* __restrict__ WTf, _Float16* __restrict__ c1F,
                        _Float16* __restrict__ c2F)
{
  long id = (long)blockIdx.x * 256 + threadIdx.x;
  if (id < 8L * 65536) {                                   // keysF x8
    int h = (int)(id & 65535);
    int copy = (int)(id >> 16);
    int j = h & 7, lane = (h >> 3) & 63, KS = (h >> 9) & 1, F = h >> 10;
    int n = F * 16 + (lane & 15);                  // mem slot
    int k = KS * 32 + ((lane >> 4) << 3) + j;      // key col
    float v = 0.f;
    if (n < MEM) {
      int rk = ranks[n];
      v = (rk < BS) ? pk[(size_t)rk * KEY + k] : memK[(size_t)n * KEY + k];
    }
    keysF[(size_t)copy * 65536 + h] = (_Float16)v;
  } else if (id < 8L * 65536 + 8L * 131072) {              // valF x8
    long i = id - 8L * 65536;
    int h = (int)(i & 131071);
    int copy = (int)(i >> 17);
    int j = h & 7, lane = (h >> 3) & 63, KS = (h >> 9) & 31, F = h >> 14;
    int nv = F * 16 + (lane & 15);                 // val col
    int jm = KS * 32 + ((j >> 2) << 4) + ((lane >> 4) << 2) + (j & 3);
    float v = 0.f;
    if (jm < MEM) {
      int rk = ranks[jm];
      v = (rk < BS) ? pv[(size_t)rk * VAL + nv] : memV[(size_t)jm * VAL + nv];
    }
    valF[(size_t)copy * 131072 + h] = (_Float16)v;
  } else {
    long i = id - (8L * 65536 + 8L * 131072);
    if (i < 7L * 65536) {                                  // WTf copies 1..7
      int copy = 1 + (int)(i >> 16); int h = (int)(i & 65535);
      WTf[(size_t)copy * 65536 + h] = WTf[h];
    } else if ((i -= 7L * 65536) < 7L * 24576) {           // c1F copies 1..7
      int copy = 1 + (int)(i / 24576); int h = (int)(i % 24576);
      c1F[(size_t)copy * 24576 + h] = c1F[h];
    } else if ((i -= 7L * 24576) < 7L * 8192) {            // c2F copies 1..7
      int copy = 1 + (int)(i >> 13); int h = (int)(i & 8191);
      c2F[(size_t)copy * 8192 + h] = c2F[h];
    }
  }
}

// ---------------------------------------------------------------------------
// fused: features + attention + controller, 16 q/wave, 8 waves/block,
// grid 512, LDS 72 KB -> 2 blocks/CU. Phase-2 K/V triple-buffered with
// 2-chunks-ahead issue and counted vmcnt(3) (drain-0 only at c==14).
// ---------------------------------------------------------------------------
__global__ __launch_bounds__(512, 4) void k_fused(
    const float* __restrict__ qx, const float* __restrict__ qy,
    const _Float16* __restrict__ WTf_, const float* __restrict__ bcomb,
    const float* __restrict__ c1_b, const float* __restrict__ c2_b,
    const float* __restrict__ c3W, const float* __restrict__ c3b,
    const _Float16* __restrict__ c1F_, const _Float16* __restrict__ c2F_,
    const _Float16* __restrict__ keysF_, const _Float16* __restrict__ valF_,
    float* __restrict__ dout)
{
  __shared__ __align__(16) char smem[73728];
  _Float16* const smh = (_Float16*)smem;
  // phase 1: Wq0=[0,32K), Wq1=[32K,64K)
  _Float16* const Wq0 = smh;
  _Float16* const Wq1 = smh + 16384;
  // phase 2: K triple-buf 3x8KB at halves {0,4096,8192};
  //          V triple-buf 3x16KB at halves {12288,20480,28672}

  const int tid  = threadIdx.x;
  const int wid  = tid >> 6;
  const int lane = tid & 63;
  const int quad = lane >> 4;
  const int l15  = lane & 15;

  // per-block decorrelators (cpy aligns with XCD: blockIdx%8 = XCD)
  const int cpy  = blockIdx.x & 7;
  const int rot  = (blockIdx.x >> 3) & 15;     // phase-2 chunk rotation
  const int qrot = (blockIdx.x >> 1) & 3;      // phase-1 quarter rotation
  const _Float16* const WTf   = WTf_   + (size_t)cpy * 65536;
  const _Float16* const c1F   = c1F_   + (size_t)cpy * 24576;
  const _Float16* const c2F   = c2F_   + (size_t)cpy * 8192;
  const _Float16* const keysF = keysF_ + (size_t)cpy * 65536;
  const _Float16* const valF  = valF_  + (size_t)cpy * 131072;

  // phase 3 per-wave scratch (dead K/V area): 2176 + 1152 halves
  _Float16* const P_s  = smh + wid * 3328;
  _Float16* const h2_s = P_s + 2176;

  const int tile = blockIdx.x * 8 + wid;       // one 16-query tile per wave
  const int q0   = tile * 16;

  float* out_pred = dout + 1;
  float* out_ret  = dout + 1 + BQ;
  const f4v fz = {0.f, 0.f, 0.f, 0.f};

  // ================= phase 1: features (dbuf 32 KB quarters, rotated) ====
  #pragma unroll
  for (int i = 0; i < 4; ++i) {                // stage quarter qrot -> Wq0
    const int t = wid * 4 + i;
    const int f = t >> 2, ksq = t & 3;
    gld16(WTf + (size_t)(f * 16 + qrot * 4 + ksq) * 512 + lane * 8, Wq0 + t * 512);
  }
  asm volatile("s_waitcnt vmcnt(0)" ::: "memory");
  __syncthreads();

  f4v acc[8];
  #pragma unroll
  for (int f = 0; f < 8; ++f) acc[f] = fz;
  const float* xr = qx + (size_t)(q0 + l15) * DIN;

  #pragma unroll
  for (int q = 0; q < 4; ++q) {
    const int qe = (q + qrot) & 3;             // processed quarter
    _Float16* const Wb = (q & 1) ? Wq1 : Wq0;
    _Float16* const Wn = (q & 1) ? Wq0 : Wq1;
    if (q < 3) {                               // stage next quarter
      const int qn = (q + 1 + qrot) & 3;
      #pragma unroll
      for (int i = 0; i < 4; ++i) {
        const int t = wid * 4 + i;
        const int f = t >> 2, ksq = t & 3;
        gld16(WTf + (size_t)(f * 16 + qn * 4 + ksq) * 512 + lane * 8,
              Wn + t * 512);
      }
    }
    #pragma unroll
    for (int ksq = 0; ksq < 4; ++ksq) {
      const int ks = qe * 4 + ksq;
      h8v a = cvt8nt(xr + ks * 32 + quad * 8);
      #pragma unroll
      for (int f = 0; f < 8; ++f) {
        h8v b = *(const h8v*)(Wb + (size_t)((f * 4 + ksq) * 64 + lane) * 8);
        acc[f] = MFMA16(a, b, acc[f]);
      }
    }
    asm volatile("s_waitcnt vmcnt(0)" ::: "memory");
    __syncthreads();
  }

  // C-layout -> A-frag registers via per-wave LDS transpose (Wq area dead).
  // qf AND pq both stay in registers (VGPR headroom: R10 ran at 64 regs).
  _Float16* tbuf = smh + wid * 2176;
  h8v pq0, pq1, qf0, qf1;
  {
    #pragma unroll
    for (int f = 0; f < 8; ++f) {
      float bb = bcomb[f * 16 + l15];
      #pragma unroll
      for (int r = 0; r < 4; ++r)
        tbuf[(quad * 4 + r) * 136 + f * 16 + l15] = (_Float16)(acc[f][r] + bb);
    }
    qf0 = *(const h8v*)&tbuf[l15 * 136 +  0 + quad * 8];
    qf1 = *(const h8v*)&tbuf[l15 * 136 + 32 + quad * 8];
    pq0 = *(const h8v*)&tbuf[l15 * 136 + 64 + quad * 8];
    pq1 = *(const h8v*)&tbuf[l15 * 136 + 96 + quad * 8];
  }
  __syncthreads();   // tbuf reads done -> K/V staging may overwrite

  // ================= phase 2: attention, triple-buffered pipeline ========
  // chunk ce: K tiles keysF[(ce*8+i)*512] -> Kbuf + i*512
  //           V tiles valF[(v*32 + ce*2 + ks2)*512] -> Vbuf + (v*2+ks2)*512
  // staging: 24 tiles / 8 waves = 3 per wave; buffers indexed mod 3.
  {
    const int s0 = rot, s1 = (rot + 1) & 15;
    #pragma unroll
    for (int i = 0; i < 3; ++i) {              // chunk rot -> buf 0
      const int t = wid * 3 + i;
      if (t < 8) gld16(keysF + (size_t)(s0 * 8 + t) * 512 + lane * 8,
                       smh + 0 * 4096 + t * 512);
      else {
        const int tv = t - 8;
        gld16(valF + (size_t)((tv >> 1) * 32 + s0 * 2 + (tv & 1)) * 512 + lane * 8,
              smh + 12288 + 0 * 8192 + tv * 512);
      }
    }
    #pragma unroll
    for (int i = 0; i < 3; ++i) {              // chunk rot+1 -> buf 1
      const int t = wid * 3 + i;
      if (t < 8) gld16(keysF + (size_t)(s1 * 8 + t) * 512 + lane * 8,
                       smh + 1 * 4096 + t * 512);
      else {
        const int tv = t - 8;
        gld16(valF + (size_t)((tv >> 1) * 32 + s1 * 2 + (tv & 1)) * 512 + lane * 8,
              smh + 12288 + 1 * 8192 + tv * 512);
      }
    }
  }
  asm volatile("s_waitcnt vmcnt(3)" ::: "memory");  // buf0 done; buf1 may fly
  __syncthreads();

  float rm = NEGF, rl = 0.f;                   // scalars (query = l15)
  f4v O[8];
  #pragma unroll
  for (int v = 0; v < 8; ++v) O[v] = fz;

  #pragma unroll 1
  for (int c = 0; c < 16; ++c) {
    const int ce  = (c + rot) & 15;            // processed chunk
    const int cur = c % 3;
    _Float16* const Kc = smh + cur * 4096;
    _Float16* const Vc = smh + 12288 + cur * 8192;

    if (c < 14) {                              // issue chunk c+2 -> buf (c+2)%3
      const int nb = (c + 2) % 3;
      const int ne = (c + 2 + rot) & 15;
      _Float16* const Kn = smh + nb * 4096;
      _Float16* const Vn = smh + 12288 + nb * 8192;
      #pragma unroll
      for (int i = 0; i < 3; ++i) {
        const int t = wid * 3 + i;
        if (t < 8)
          gld16(keysF + (size_t)(ne * 8 + t) * 512 + lane * 8, Kn + t * 512);
        else {
          const int tv = t - 8;
          gld16(valF + (size_t)((tv >> 1) * 32 + ne * 2 + (tv & 1)) * 512 + lane * 8,
                Vn + tv * 512);
        }
      }
    }

    // ---- QK^T (swapped): 8 MFMA, S lane-local ----
    f4v S[4];
    #pragma unroll
    for (int f = 0; f < 4; ++f) S[f] = fz;
    #pragma unroll
    for (int f = 0; f < 4; ++f) {
      h8v b0 = *(const h8v*)(Kc + (size_t)(f * 2 + 0) * 512 + lane * 8);
      h8v b1 = *(const h8v*)(Kc + (size_t)(f * 2 + 1) * 512 + lane * 8);
      S[f] = MFMA16(b0, pq0, S[f]);
      S[f] = MFMA16(b1, pq1, S[f]);
    }

    // ---- register softmax (16 vals/lane), defer-rescale (exact skip) ----
    float cm = NEGF;
    #pragma unroll
    for (int f = 0; f < 4; ++f) {
      const int sb = ce * 64 + f * 16 + quad * 4;
      #pragma unroll
      for (int r = 0; r < 4; ++r) {
        float s = (sb + r < MEM) ? S[f][r] : NEGF;
        S[f][r] = s;
        cm = fmaxf(cm, s);
      }
    }
    cm = fmaxf(cm, __shfl_xor(cm, 16));
    cm = fmaxf(cm, __shfl_xor(cm, 32));
    if (__any(cm > rm)) {                      // skipped path is bitwise
      float mn = fmaxf(rm, cm);                // identical (al would be 1.0)
      float al = __expf(rm - mn);
      rm = mn;
      float alO[4];
      #pragma unroll
      for (int r = 0; r < 4; ++r) alO[r] = __shfl(al, quad * 4 + r);
      #pragma unroll
      for (int v = 0; v < 8; ++v)
        #pragma unroll
        for (int r = 0; r < 4; ++r) O[v][r] *= alO[r];
      rl *= al;
    }
    float psl = 0.f;
    #pragma unroll
    for (int f = 0; f < 4; ++f)
      #pragma unroll
      for (int r = 0; r < 4; ++r) {
        float p = __expf(S[f][r] - rm);
        S[f][r] = p;
        psl += p;
      }
    rl += psl;

    // ---- P@V: 16 MFMA, A-frag = lane's own S (permuted valF) ----
    #pragma unroll
    for (int ks2 = 0; ks2 < 2; ++ks2) {
      h8v a;
      #pragma unroll
      for (int e = 0; e < 4; ++e) {
        a[e]     = (_Float16)S[2 * ks2][e];
        a[e + 4] = (_Float16)S[2 * ks2 + 1][e];
      }
      #pragma unroll
      for (int v = 0; v < 8; ++v) {
        h8v b = *(const h8v*)(Vc + (size_t)(v * 2 + ks2) * 512 + lane * 8);
        O[v] = MFMA16(a, b, O[v]);
      }
    }

    // counted wait: only ensure buf[(c+1)%3] (issued at c-1) is complete.
    // The 3 newest loads (for c+2, issued this iter) stay in flight.
    if (c < 14) {
      asm volatile("s_waitcnt vmcnt(3)" ::: "memory");
    } else if (c == 14) {
      asm volatile("s_waitcnt vmcnt(0)" ::: "memory");
    }
    __syncthreads();
  }

  // ---- final denominator: reduce over quads, redistribute to O layout ----
  rl += __shfl_xor(rl, 16); rl += __shfl_xor(rl, 32);
  float rlO[4];
  #pragma unroll
  for (int r = 0; r < 4; ++r) rlO[r] = __shfl(rl, quad * 4 + r);

  // ================= phase 3: epilogue =================
  // (loop's trailing barrier protects the K/V area before scratch overlay)
  // retrieved -> LDS fp16
  #pragma unroll
  for (int v = 0; v < 8; ++v)
    #pragma unroll
    for (int r = 0; r < 4; ++r)
      P_s[(quad * 4 + r) * 136 + v * 16 + l15] = (_Float16)(O[v][r] / rlO[r]);

  // contiguous nt stores: 8 iters x (64 lanes x 16 B)
  #pragma unroll
  for (int it = 0; it < 8; ++it) {
    int flat = it * 256 + lane * 4;
    int row = flat >> 7, col = flat & 127;
    h4v t = *(const h4v*)&P_s[row * 136 + col];
    f4v o;
    o.x = (float)t[0]; o.y = (float)t[1]; o.z = (float)t[2]; o.w = (float)t[3];
    __builtin_nontemporal_store(o, (f4v*)(out_ret + (size_t)q0 * VAL + flat));
  }

  // c1: relu([qf|ret] @ c1_W + b); b-frags directly from L2 (per-block copy)
  {
    f4v H[8];
    #pragma unroll
    for (int f = 0; f < 8; ++f) H[f] = fz;
    #pragma unroll
    for (int ks = 0; ks < 6; ++ks) {
      const int k0 = ks * 32;
      h8v a = (ks == 0) ? qf0 : (ks == 1) ? qf1
               : *(const h8v*)&P_s[l15 * 136 + (k0 - 64) + quad * 8];
      #pragma unroll
      for (int f = 0; f < 8; ++f) {
        h8v b = *(const h8v*)(c1F + (size_t)(f * 6 + ks) * 512 + lane * 8);
        H[f] = MFMA16(a, b, H[f]);
      }
    }
    #pragma unroll
    for (int f = 0; f < 8; ++f) {
      float bb = c1_b[f * 16 + l15];
      #pragma unroll
      for (int r = 0; r < 4; ++r)
        P_s[(quad * 4 + r) * 136 + f * 16 + l15] =
            (_Float16)fmaxf(0.f, H[f][r] + bb);
    }
  }

  // c2: relu(h1 @ c2_W + b) -> h2
  {
    f4v G[4];
    #pragma unroll
    for (int f = 0; f < 4; ++f) G[f] = fz;
    #pragma unroll
    for (int ks = 0; ks < 4; ++ks) {
      h8v a = *(const h8v*)&P_s[l15 * 136 + ks * 32 + quad * 8];
      #pragma unroll
      for (int f = 0; f < 4; ++f) {
        h8v b = *(const h8v*)(c2F + (size_t)(f * 4 + ks) * 512 + lane * 8);
        G[f] = MFMA16(a, b, G[f]);
      }
    }
    #pragma unroll
    for (int f = 0; f < 4; ++f) {
      float bb = c2_b[f * 16 + l15];
      #pragma unroll
      for (int r = 0; r < 4; ++r)
        h2_s[(quad * 4 + r) * 72 + f * 16 + l15] =
            (_Float16)fmaxf(0.f, G[f][r] + bb);
    }
  }

  // c3 + loss (4 lanes per query row)
  float lsum;
  {
    const int prow = lane >> 2, pj = lane & 3;
    float s = 0.f;
    #pragma unroll
    for (int k = 0; k < 16; ++k) {
      int kk = pj * 16 + k;
      s += (float)h2_s[prow * 72 + kk] * c3W[kk];
    }
    s += __shfl_xor(s, 1);
    s += __shfl_xor(s, 2);
    float pred = s + c3b[0];
    float diff = pred - qy[q0 + prow];
    if (pj == 0) out_pred[q0 + prow] = pred;
    lsum = diff * diff;                        // each row counted 4x
  }
  #pragma unroll
  for (int m = 1; m < 64; m <<= 1) lsum += __shfl_xor(lsum, m);
  if (lane == 0) atomicAdd(dout, lsum * (1.0f / (4.0f * (float)BQ)));
}

// ---------------------------------------------------------------------------
extern "C" void kernel_launch(void* const* d_in, const int* in_sizes, int n_in,
                              void* d_out, int out_size, void* d_ws, size_t ws_size,
                              hipStream_t stream)
{
  const float* support_x = (const float*)d_in[0];
  const float* support_y = (const float*)d_in[1];
  const float* query_x   = (const float*)d_in[2];
  const float* query_y   = (const float*)d_in[3];
  const float* base_W    = (const float*)d_in[4];
  const float* base_b    = (const float*)d_in[5];
  const float* kp_W      = (const float*)d_in[6];
  const float* kp_b      = (const float*)d_in[7];
  const float* vp_W      = (const float*)d_in[8];
  const float* vp_b      = (const float*)d_in[9];
  const float* mem_keys  = (const float*)d_in[10];
  const float* mem_vals  = (const float*)d_in[11];
  const float* mem_age   = (const float*)d_in[12];
  const float* c1_W      = (const float*)d_in[13];
  const float* c1_b      = (const float*)d_in[14];
  const float* c2_W      = (const float*)d_in[15];
  const float* c2_b      = (const float*)d_in[16];
  const float* c3_W      = (const float*)d_in[17];
  const float* c3_b      = (const float*)d_in[18];

  char* w = (char*)d_ws;                        // ~5.2 MB used
  _Float16* WTf   = (_Float16*)(w + 0);         // 8 x 128 KB, ends 1048576
  _Float16* c1F   = (_Float16*)(w + 1048576);   // 8 x 48 KB, ends 1441792
  _Float16* c2F   = (_Float16*)(w + 1441792);   // 8 x 16 KB, ends 1572864
  _Float16* keysF = (_Float16*)(w + 1572864);   // 8 x 128 KB, ends 2621440
  _Float16* valF  = (_Float16*)(w + 2621440);   // 8 x 256 KB, ends 4718592
  _Float16* vpWt  = (_Float16*)(w + 4718592);   // 32 KB, ends 4751360
  float*    bcomb = (float*)   (w + 4751360);   // 512 B, ends 4751872
  int*      ranks = (int*)     (w + 4751872);   // 4 KB, ends 4755968
  float*    pkeys = (float*)   (w + 4755968);   // 128 KB, ends 4887040
  float*    pvals = (float*)   (w + 4887040);   // 256 KB, ends 5149184

  float* out = (float*)d_out;

  hipLaunchKernelGGL(k_prep1, dim3(453), dim3(256), 0, stream,
                     base_W, base_b, kp_W, kp_b, vp_W, c1_W, c2_W, mem_age,
                     WTf, bcomb, vpWt, c1F, c2F, ranks, out);
  hipLaunchKernelGGL(k_prep2, dim3(64), dim3(64), 0, stream,
                     support_x, support_y, WTf, bcomb, vpWt, vp_b, pkeys, pvals);
  hipLaunchKernelGGL(k_prep3, dim3(8832), dim3(256), 0, stream,
                     ranks, pkeys, pvals, mem_keys, mem_vals, keysF, valF,
                     WTf, c1F, c2F);
  hipLaunchKernelGGL(k_fused, dim3(BQ / 128), dim3(512), 0, stream,
                     query_x, query_y, WTf, bcomb, c1_b, c2_b, c3_W, c3_b,
                     c1F, c2F, keysF, valF, out);
}